// Round 4
// baseline (877.611 us; speedup 1.0000x reference)
//
#include <hip/hip_runtime.h>
#include <hip/hip_bf16.h>
#include <math.h>

// Problem constants
#define BATCH   256
#define KMEM    10          // K
#define NPROT   200         // N*K
#define DDIM    512
#define NROWS   (BATCH * NPROT)   // 51200
#define TINV    10.0f       // 1/T
#define TILE    32          // j-rows staged in LDS per tile
#define APB     100         // anchors per block (2 blocks per batch elem)
#define NBLK_B  (BATCH * 2) // 512 main-kernel blocks

__device__ __forceinline__ float wave_red(float x) {
    x += __shfl_xor(x, 32);
    x += __shfl_xor(x, 16);
    x += __shfl_xor(x, 8);
    x += __shfl_xor(x, 4);
    x += __shfl_xor(x, 2);
    x += __shfl_xor(x, 1);
    return x;
}

// Kernel 1: inverse L2 norm per row (51200 rows of 512 fp32)
__global__ __launch_bounds__(256) void knorm(const float* __restrict__ P,
                                             float* __restrict__ invn) {
    int wave = threadIdx.x >> 6;
    int lane = threadIdx.x & 63;
    int row  = blockIdx.x * 4 + wave;
    if (row >= NROWS) return;
    const float4* r = (const float4*)(P + (size_t)row * DDIM);
    float4 a = r[lane];
    float4 b = r[lane + 64];
    float s = a.x*a.x + a.y*a.y + a.z*a.z + a.w*a.w
            + b.x*b.x + b.y*b.y + b.z*b.z + b.w*b.w;
    s = wave_red(s);
    if (lane == 0) invn[row] = 1.0f / sqrtf(s);
}

__device__ __forceinline__ void load_anchor(const float* Pb, int m, float sc,
                                            int lane, float am[8]) {
    const float4* r = (const float4*)(Pb + (size_t)m * DDIM + lane * 8);
    float4 x = r[0];
    float4 y = r[1];
    am[0] = x.x * sc; am[1] = x.y * sc; am[2] = x.z * sc; am[3] = x.w * sc;
    am[4] = y.x * sc; am[5] = y.y * sc; am[6] = y.z * sc; am[7] = y.w * sc;
}

// Kernel 2: main — per block: batch elem b, anchors [a0, a0+100)
__global__ __launch_bounds__(256) void kmain(const float* __restrict__ P,
                                             const float* __restrict__ invn,
                                             float* __restrict__ partial) {
    __shared__ __hip_bfloat16 tileS[TILE][DDIM];   // 32 KB
    __shared__ float s1[APB];
    __shared__ float s2[APB];
    __shared__ float red[256];

    const int tid  = threadIdx.x;
    const int lane = tid & 63;
    const int wave = tid >> 6;
    const int b    = blockIdx.x >> 1;
    const int a0   = (blockIdx.x & 1) * APB;

    const float* Pb   = P + (size_t)b * NPROT * DDIM;
    const float* invb = invn + b * NPROT;

    for (int i = tid; i < APB; i += 256) { s1[i] = 0.f; s2[i] = 0.f; }
    __syncthreads();

    for (int j0 = 0; j0 < NPROT; j0 += TILE) {
        const int jn = (NPROT - j0) < TILE ? (NPROT - j0) : TILE;

        // ---- stage jn normalized rows as bf16 into LDS (coalesced) ----
        const int nf = jn * (DDIM / 4);
        for (int f = tid; f < nf; f += 256) {
            int j  = f >> 7;            // f / 128 (128 float4 per row)
            int d4 = (f & 127) << 2;    // element offset within row
            float4 v = *(const float4*)(Pb + (size_t)(j0 + j) * DDIM + d4);
            float sc = invb[j0 + j];
            union { __hip_bfloat16 h[4]; uint2 u; } pk;
            pk.h[0] = __float2bfloat16(v.x * sc);
            pk.h[1] = __float2bfloat16(v.y * sc);
            pk.h[2] = __float2bfloat16(v.z * sc);
            pk.h[3] = __float2bfloat16(v.w * sc);
            *(uint2*)(&tileS[j][d4]) = pk.u;
        }
        __syncthreads();

        // ---- each wave: chunks of 4 anchors vs the staged tile ----
        for (int c0 = wave * 4; c0 < APB; c0 += 16) {
            const int m0 = a0 + c0 + 0, m1 = a0 + c0 + 1;
            const int m2 = a0 + c0 + 2, m3 = a0 + c0 + 3;
            const int cls0 = m0 / KMEM, cls1 = m1 / KMEM;
            const int cls2 = m2 / KMEM, cls3 = m3 / KMEM;

            float am0[8], am1[8], am2[8], am3[8];
            load_anchor(Pb, m0, invb[m0], lane, am0);
            load_anchor(Pb, m1, invb[m1], lane, am1);
            load_anchor(Pb, m2, invb[m2], lane, am2);
            load_anchor(Pb, m3, invb[m3], lane, am3);

            float r1_0 = 0.f, r1_1 = 0.f, r1_2 = 0.f, r1_3 = 0.f;
            float r2_0 = 0.f, r2_1 = 0.f, r2_2 = 0.f, r2_3 = 0.f;

            for (int jj = 0; jj < jn; jj++) {
                const int jgl  = j0 + jj;
                const int jcls = jgl / KMEM;

                float4 raw = *(const float4*)(&tileS[jj][lane * 8]);
                const unsigned* up = (const unsigned*)&raw;
                float fj[8];
                #pragma unroll
                for (int e = 0; e < 4; e++) {
                    unsigned u  = up[e];
                    fj[2*e]     = __uint_as_float(u << 16);
                    fj[2*e + 1] = __uint_as_float(u & 0xffff0000u);
                }

                float d0 = 0.f, d1 = 0.f, d2 = 0.f, d3 = 0.f;
                #pragma unroll
                for (int e = 0; e < 8; e++) {
                    d0 = fmaf(am0[e], fj[e], d0);
                    d1 = fmaf(am1[e], fj[e], d1);
                    d2 = fmaf(am2[e], fj[e], d2);
                    d3 = fmaf(am3[e], fj[e], d3);
                }
                d0 = wave_red(d0);
                d1 = wave_red(d1);
                d2 = wave_red(d2);
                d3 = wave_red(d3);

                // uniform (scalar) conditions across the wave
                if (jgl != m0) { r1_0 += __expf(d0 * TINV); if (jcls == cls0) r2_0 += d0; }
                if (jgl != m1) { r1_1 += __expf(d1 * TINV); if (jcls == cls1) r2_1 += d1; }
                if (jgl != m2) { r1_2 += __expf(d2 * TINV); if (jcls == cls2) r2_2 += d2; }
                if (jgl != m3) { r1_3 += __expf(d3 * TINV); if (jcls == cls3) r2_3 += d3; }
            }

            if (lane == 0) {
                s1[c0 + 0] += r1_0; s2[c0 + 0] += r2_0;
                s1[c0 + 1] += r1_1; s2[c0 + 1] += r2_1;
                s1[c0 + 2] += r1_2; s2[c0 + 2] += r2_2;
                s1[c0 + 3] += r1_3; s2[c0 + 3] += r2_3;
            }
        }
        __syncthreads();
    }

    // ---- epilogue: per-anchor loss, block reduction ----
    float v = 0.f;
    if (tid < APB) {
        v = logf(s1[tid]) - s2[tid] * (TINV / 9.0f);  // /(T*(K-1))
    }
    red[tid] = v;
    __syncthreads();
    for (int sx = 128; sx > 0; sx >>= 1) {
        if (tid < sx) red[tid] += red[tid + sx];
        __syncthreads();
    }
    if (tid == 0) partial[blockIdx.x] = red[0];
}

// Kernel 3: final reduction of 512 block partials (fp64) + scale
__global__ __launch_bounds__(256) void kfinal(const float* __restrict__ partial,
                                              float* __restrict__ out) {
    __shared__ double red[256];
    int tid = threadIdx.x;
    double v = (double)partial[tid] + (double)partial[tid + 256];
    red[tid] = v;
    __syncthreads();
    for (int sx = 128; sx > 0; sx >>= 1) {
        if (tid < sx) red[tid] += red[tid + sx];
        __syncthreads();
    }
    // ALPHA / (BNORM * N * K * D) = 0.1 / 102400
    if (tid == 0) out[0] = (float)(red[0] * (0.1 / 102400.0));
}

extern "C" void kernel_launch(void* const* d_in, const int* in_sizes, int n_in,
                              void* d_out, int out_size, void* d_ws, size_t ws_size,
                              hipStream_t stream) {
    const float* P = (const float*)d_in[0];
    float* invn    = (float*)d_ws;                 // 51200 floats
    float* partial = invn + NROWS;                 // 512 floats
    float* out     = (float*)d_out;

    knorm<<<NROWS / 4, 256, 0, stream>>>(P, invn);
    kmain<<<NBLK_B, 256, 0, stream>>>(P, invn, partial);
    kfinal<<<1, 256, 0, stream>>>(partial, out);
}

// Round 5
// 33.721 us; speedup vs baseline: 26.0255x; 26.0255x over previous
//
#include <hip/hip_runtime.h>
#include <hip/hip_bf16.h>
#include <math.h>

// Problem constants
#define BATCH   256
#define KMEM    10          // K (class size)
#define NPROT   200         // N*K prototypes per batch elem
#define DDIM    512
#define TINVF   10.0f       // 1/T
#define KSLAB   64          // K-columns staged per slab
#define NSLAB   (DDIM / KSLAB)   // 8
#define RPAD    256         // rows padded to 16 fragments
#define ROWB    128         // bytes per LDS row (64 bf16)
#define NSEG    800         // 200 rows x 4 segments of 16 floats

typedef __attribute__((ext_vector_type(8))) short short8;
typedef __attribute__((ext_vector_type(4))) float f32x4;

// bf16 round-to-nearest-even (finite inputs)
__device__ __forceinline__ unsigned short f2bf(float v) {
    unsigned u = __float_as_uint(v);
    return (unsigned short)((u + 0x7fffu + ((u >> 16) & 1u)) >> 16);
}

__device__ __forceinline__ void pack16(const float4 c[4], uint4& p0, uint4& p1, float& sq) {
    union { unsigned short us[16]; uint4 u[2]; } w;
    const float* f = (const float*)c;
    #pragma unroll
    for (int e = 0; e < 16; e++) {
        float v = f[e];
        sq = fmaf(v, v, sq);
        w.us[e] = f2bf(v);
    }
    p0 = w.u[0];
    p1 = w.u[1];
}

// One block per batch element. 512 threads = 8 waves (4 x 2 fragment grid).
// G_raw = Praw . Praw^T via MFMA on bf16; normalization (invn[m]*invn[j]),
// diagonal skip, class masks, exp/log all in the epilogue.
__global__ __launch_bounds__(512, 2) void kmain(const float* __restrict__ P,
                                                float* __restrict__ partial) {
    __shared__ char  slab[2][RPAD * ROWB];   // 64 KB, XOR-swizzled bf16 tiles
    __shared__ float normpart[NSEG];
    __shared__ float invn_s[RPAD];
    __shared__ float s1buf[2][RPAD];
    __shared__ float s2buf[2][RPAD];
    __shared__ float red[512];

    const int tid  = threadIdx.x;
    const int lane = tid & 63;
    const int wave = tid >> 6;   // 0..7
    const int wr   = wave >> 1;  // 0..3 : i-frags [wr*4, wr*4+4)
    const int wc   = wave & 1;   // 0..1 : j-frags [wc*8, wc*8+8)
    const int b    = blockIdx.x;
    const float* Pb = P + (size_t)b * NPROT * DDIM;

    // zero pad rows 200..255 in BOTH buffers (never rewritten)
    for (int z = tid; z < 2 * 56 * 8; z += 512) {
        int bsel = z / (56 * 8);
        int slot = z % (56 * 8);
        int row  = NPROT + (slot >> 3);
        *(uint4*)(&slab[bsel][row * ROWB + (slot & 7) * 16]) = make_uint4(0, 0, 0, 0);
    }

    // staging assignment: seg idx -> (row, 16-float segment)
    const int  idx0 = tid;                 // < 800 always
    const int  row0 = idx0 >> 2, seg0 = idx0 & 3;
    const int  idx1 = tid + 512;
    const bool has1 = (idx1 < NSEG);       // threads 0..287
    const int  row1 = idx1 >> 2, seg1 = idx1 & 3;

    float sq0 = 0.f, sq1 = 0.f;

    // prefetch slab 0
    float4 curA[4], curB[4];
    {
        const float4* sA = (const float4*)(Pb + (size_t)row0 * DDIM + seg0 * 16);
        curA[0] = sA[0]; curA[1] = sA[1]; curA[2] = sA[2]; curA[3] = sA[3];
        if (has1) {
            const float4* sB = (const float4*)(Pb + (size_t)row1 * DDIM + seg1 * 16);
            curB[0] = sB[0]; curB[1] = sB[1]; curB[2] = sB[2]; curB[3] = sB[3];
        }
    }

    f32x4 acc[4][8];
    #pragma unroll
    for (int i = 0; i < 4; i++)
        #pragma unroll
        for (int j = 0; j < 8; j++)
            acc[i][j] = (f32x4)(0.f);

    const int swz0 = (row0 & 7) << 4;
    const int swz1 = (row1 & 7) << 4;

    for (int s = 0; s < NSLAB; s++) {
        char* buf = slab[s & 1];

        // ---- convert + swizzled LDS write + sumsq ----
        {
            uint4 p0, p1;
            pack16(curA, p0, p1, sq0);
            int byte0 = row0 * ROWB + seg0 * 32;
            *(uint4*)(&buf[(byte0     ) ^ swz0]) = p0;
            *(uint4*)(&buf[(byte0 + 16) ^ swz0]) = p1;
        }
        if (has1) {
            uint4 p0, p1;
            pack16(curB, p0, p1, sq1);
            int byte0 = row1 * ROWB + seg1 * 32;
            *(uint4*)(&buf[(byte0     ) ^ swz1]) = p0;
            *(uint4*)(&buf[(byte0 + 16) ^ swz1]) = p1;
        }
        __syncthreads();

        // ---- prefetch next slab (overlaps MFMA below) ----
        float4 nxtA[4], nxtB[4];
        if (s + 1 < NSLAB) {
            const float4* sA = (const float4*)(Pb + (size_t)row0 * DDIM + (s + 1) * KSLAB + seg0 * 16);
            nxtA[0] = sA[0]; nxtA[1] = sA[1]; nxtA[2] = sA[2]; nxtA[3] = sA[3];
            if (has1) {
                const float4* sB = (const float4*)(Pb + (size_t)row1 * DDIM + (s + 1) * KSLAB + seg1 * 16);
                nxtB[0] = sB[0]; nxtB[1] = sB[1]; nxtB[2] = sB[2]; nxtB[3] = sB[3];
            }
        }

        // ---- MFMA: 2 k-steps of 32 over this slab ----
        #pragma unroll
        for (int ks = 0; ks < 2; ks++) {
            const int kb = (ks * 32 + (lane >> 4) * 8) * 2;  // byte offset of k-chunk
            short8 af[4];
            #pragma unroll
            for (int i = 0; i < 4; i++) {
                int row = (wr * 4 + i) * 16 + (lane & 15);
                af[i] = *(const short8*)(&buf[(row * ROWB + kb) ^ ((row & 7) << 4)]);
            }
            #pragma unroll
            for (int j = 0; j < 8; j++) {
                int row = (wc * 8 + j) * 16 + (lane & 15);
                short8 bf = *(const short8*)(&buf[(row * ROWB + kb) ^ ((row & 7) << 4)]);
                #pragma unroll
                for (int i = 0; i < 4; i++)
                    acc[i][j] = __builtin_amdgcn_mfma_f32_16x16x32_bf16(af[i], bf, acc[i][j], 0, 0, 0);
            }
        }

        #pragma unroll
        for (int q = 0; q < 4; q++) { curA[q] = nxtA[q]; curB[q] = nxtB[q]; }
    }

    // ---- norms: 4 seg-partials per row -> invn ----
    normpart[idx0] = sq0;
    if (has1) normpart[idx1] = sq1;
    __syncthreads();
    if (tid < RPAD) {
        float iv = 0.f;
        if (tid < NPROT) {
            float ns = normpart[4 * tid] + normpart[4 * tid + 1]
                     + normpart[4 * tid + 2] + normpart[4 * tid + 3];
            iv = rsqrtf(ns);
        }
        invn_s[tid] = iv;   // 0 for padded rows -> g stays 0
    }
    __syncthreads();

    // ---- epilogue: normalize, mask, exp/class sums, 16-lane reduce ----
    float ijn[8]; int jg[8], jdiv[8];
    #pragma unroll
    for (int j = 0; j < 8; j++) {
        jg[j]   = wc * 128 + j * 16 + (lane & 15);
        ijn[j]  = invn_s[jg[j]];
        jdiv[j] = jg[j] / KMEM;
    }
    #pragma unroll
    for (int i = 0; i < 4; i++) {
        #pragma unroll
        for (int r = 0; r < 4; r++) {
            const int m = wr * 64 + i * 16 + (lane >> 4) * 4 + r;
            const float im = invn_s[m];
            const int mdiv = m / KMEM;
            float s1 = 0.f, s2 = 0.f;
            #pragma unroll
            for (int j = 0; j < 8; j++) {
                float g = acc[i][j][r] * im * ijn[j];
                bool valid = (jg[j] < NPROT) && (m < NPROT) && (jg[j] != m);
                s1 += valid ? __expf(g * TINVF) : 0.f;
                s2 += (valid && (jdiv[j] == mdiv)) ? g : 0.f;
            }
            #pragma unroll
            for (int d = 1; d < 16; d <<= 1) {
                s1 += __shfl_xor(s1, d);
                s2 += __shfl_xor(s2, d);
            }
            if ((lane & 15) == 0) {
                s1buf[wc][m] = s1;
                s2buf[wc][m] = s2;
            }
        }
    }
    __syncthreads();

    // ---- per-anchor loss + block reduction ----
    float v = 0.f;
    if (tid < NPROT) {
        float S1 = s1buf[0][tid] + s1buf[1][tid];
        float S2 = s2buf[0][tid] + s2buf[1][tid];
        v = logf(S1) - S2 * (TINVF / 9.0f);   // /(T*(K-1))
    }
    red[tid] = v;
    __syncthreads();
    for (int sx = 256; sx > 0; sx >>= 1) {
        if (tid < sx) red[tid] += red[tid + sx];
        __syncthreads();
    }
    if (tid == 0) partial[b] = red[0];
}

// final reduction of 256 block partials (fp64) + scale
__global__ __launch_bounds__(256) void kfinal(const float* __restrict__ partial,
                                              float* __restrict__ out) {
    __shared__ double red[256];
    int tid = threadIdx.x;
    red[tid] = (double)partial[tid];
    __syncthreads();
    for (int sx = 128; sx > 0; sx >>= 1) {
        if (tid < sx) red[tid] += red[tid + sx];
        __syncthreads();
    }
    // ALPHA / (BNORM * N * K * D) = 0.1 / 102400
    if (tid == 0) out[0] = (float)(red[0] * (0.1 / 102400.0));
}

extern "C" void kernel_launch(void* const* d_in, const int* in_sizes, int n_in,
                              void* d_out, int out_size, void* d_ws, size_t ws_size,
                              hipStream_t stream) {
    const float* P = (const float*)d_in[0];
    float* partial = (float*)d_ws;   // 256 floats
    float* out     = (float*)d_out;

    kmain<<<BATCH, 512, 0, stream>>>(P, partial);
    kfinal<<<1, 256, 0, stream>>>(partial, out);
}